// Round 10
// baseline (62.724 us; speedup 1.0000x reference)
//
#include <hip/hip_runtime.h>

static constexpr int BATCH  = 65536;
static constexpr int DDIM   = 512;
static constexpr int NCLS   = 7;
static constexpr int SLICE  = NCLS * DDIM;      // 3584 class-sum floats
static constexpr int SLICEP = SLICE + 16;       // + 16-float scalar chunk
// scalar chunk layout: [0]=sumsq [1]=l1 [2]=ce [3..9]=counts[0..6]
static constexpr int NRED   = NCLS * 16;        // 112 reduce blocks

// Fused main pass, 512 threads = 4 row-phases x 128 float4-columns.
// PHASE-SPLIT streaming: loop 1 reads ONLY features (single address stream ->
// HBM row-buffer locality, like the 6.3 TB/s copy ubench), loop 2 reads ONLY
// attention_weights. Predicated class accumulate (no branches -> no spill).
// All block results leave as plain coalesced stores into a private slice.
template <int RPB>
__global__ __launch_bounds__(512, 6) void k_main(const float4* __restrict__ F,
                                                 const float4* __restrict__ A,
                                                 const int* __restrict__ tg,
                                                 const float* __restrict__ outputs,
                                                 float* __restrict__ part) {
  const int tid  = threadIdx.x;
  const int bid  = blockIdx.x;
  const int c4   = tid & 127;   // float4 column (0..127)
  const int ph   = tid >> 7;    // row phase 0..3 (wave-uniform)
  const int base = bid * RPB;

  float4 acc[NCLS];
#pragma unroll
  for (int c = 0; c < NCLS; ++c) acc[c] = make_float4(0.f, 0.f, 0.f, 0.f);
  float sumsq = 0.f, l1 = 0.f;

  // ---- Loop 1: features only (sumsq + per-class sums) ----
#pragma unroll 4
  for (int r = base; r < base + RPB; r += 8) {
    const int4 ta = *reinterpret_cast<const int4*>(tg + r);      // rows r..r+3
    const int4 tb = *reinterpret_cast<const int4*>(tg + r + 4);  // rows r+4..r+7
    const size_t i0 = (size_t)(r + ph) * 128 + c4;
    const float4 f0 = F[i0];
    const float4 f1 = F[i0 + 512];   // row + 4
    const int t0 = (ph == 0) ? ta.x : (ph == 1) ? ta.y : (ph == 2) ? ta.z : ta.w;
    const int t1 = (ph == 0) ? tb.x : (ph == 1) ? tb.y : (ph == 2) ? tb.z : tb.w;

    sumsq = fmaf(f0.x, f0.x, sumsq); sumsq = fmaf(f0.y, f0.y, sumsq);
    sumsq = fmaf(f0.z, f0.z, sumsq); sumsq = fmaf(f0.w, f0.w, sumsq);
    sumsq = fmaf(f1.x, f1.x, sumsq); sumsq = fmaf(f1.y, f1.y, sumsq);
    sumsq = fmaf(f1.z, f1.z, sumsq); sumsq = fmaf(f1.w, f1.w, sumsq);

#pragma unroll
    for (int c = 0; c < NCLS; ++c) {
      acc[c].x += (t0 == c) ? f0.x : 0.f;
      acc[c].y += (t0 == c) ? f0.y : 0.f;
      acc[c].z += (t0 == c) ? f0.z : 0.f;
      acc[c].w += (t0 == c) ? f0.w : 0.f;
      acc[c].x += (t1 == c) ? f1.x : 0.f;
      acc[c].y += (t1 == c) ? f1.y : 0.f;
      acc[c].z += (t1 == c) ? f1.z : 0.f;
      acc[c].w += (t1 == c) ? f1.w : 0.f;
    }
  }

  // ---- Loop 2: attention only (L1) ----
#pragma unroll 4
  for (int r = base; r < base + RPB; r += 8) {
    const size_t i0 = (size_t)(r + ph) * 128 + c4;
    const float4 w0 = A[i0];
    const float4 w1 = A[i0 + 512];
    l1 += fabsf(w0.x) + fabsf(w0.y) + fabsf(w0.z) + fabsf(w0.w) +
          fabsf(w1.x) + fabsf(w1.y) + fabsf(w1.z) + fabsf(w1.w);
  }

  // Fold phases 1..3 onto phase 0 via LDS (2 rounds). [..][33] = conflict-free.
  __shared__ float red[256][33];
  if (ph >= 2) {
    float* row = red[(ph - 2) * 128 + c4];
#pragma unroll
    for (int c = 0; c < NCLS; ++c) {
      row[c * 4 + 0] = acc[c].x; row[c * 4 + 1] = acc[c].y;
      row[c * 4 + 2] = acc[c].z; row[c * 4 + 3] = acc[c].w;
    }
    row[28] = sumsq; row[29] = l1;
  }
  __syncthreads();
  if (ph < 2) {
    const float* row = red[ph * 128 + c4];
#pragma unroll
    for (int c = 0; c < NCLS; ++c) {
      acc[c].x += row[c * 4 + 0]; acc[c].y += row[c * 4 + 1];
      acc[c].z += row[c * 4 + 2]; acc[c].w += row[c * 4 + 3];
    }
    sumsq += row[28]; l1 += row[29];
  }
  __syncthreads();
  if (ph == 1) {
    float* row = red[c4];
#pragma unroll
    for (int c = 0; c < NCLS; ++c) {
      row[c * 4 + 0] = acc[c].x; row[c * 4 + 1] = acc[c].y;
      row[c * 4 + 2] = acc[c].z; row[c * 4 + 3] = acc[c].w;
    }
    row[28] = sumsq; row[29] = l1;
  }
  __syncthreads();

  __shared__ float s2[2], s3[2];
  if (ph == 0) {
    const float* row = red[c4];
#pragma unroll
    for (int c = 0; c < NCLS; ++c) {
      acc[c].x += row[c * 4 + 0]; acc[c].y += row[c * 4 + 1];
      acc[c].z += row[c * 4 + 2]; acc[c].w += row[c * 4 + 3];
    }
    sumsq += row[28]; l1 += row[29];

    // Plain coalesced stores into this block's private slice. No RMW.
    float4* __restrict__ myp = reinterpret_cast<float4*>(part + (size_t)bid * SLICEP);
#pragma unroll
    for (int c = 0; c < NCLS; ++c) myp[c * 128 + c4] = acc[c];

    float bs = sumsq, bl = l1;
#pragma unroll
    for (int off = 32; off > 0; off >>= 1) {
      bs += __shfl_down(bs, off);
      bl += __shfl_down(bl, off);
    }
    if ((tid & 63) == 0) { s2[tid >> 6] = bs; s3[tid >> 6] = bl; }
  }

  // CE + per-class counts over this block's rows, wave-parallel.
  constexpr int NACT = (RPB / 64 < 8) ? RPB / 64 : 8;   // active waves
  __shared__ float ce_w[8];
  __shared__ float cw_w[8][8];
  const int lane = tid & 63, wid = tid >> 6;
  if (wid < NACT) {
    float ce = 0.f;
    float cw[NCLS];
#pragma unroll
    for (int c = 0; c < NCLS; ++c) cw[c] = 0.f;
    for (int r0 = wid * 64; r0 < RPB; r0 += NACT * 64) {
      const int row = base + r0 + lane;
      const float* o = outputs + (size_t)row * NCLS;
      const float x0 = o[0], x1 = o[1], x2 = o[2], x3 = o[3],
                  x4 = o[4], x5 = o[5], x6 = o[6];
      const float m = fmaxf(fmaxf(fmaxf(x0, x1), fmaxf(x2, x3)),
                            fmaxf(fmaxf(x4, x5), x6));
      const float s = expf(x0 - m) + expf(x1 - m) + expf(x2 - m) + expf(x3 - m) +
                      expf(x4 - m) + expf(x5 - m) + expf(x6 - m);
      const int t = tg[row];
      const float xt = (t == 0) ? x0 : (t == 1) ? x1 : (t == 2) ? x2 :
                       (t == 3) ? x3 : (t == 4) ? x4 : (t == 5) ? x5 : x6;
      ce += (m - xt) + logf(s);
#pragma unroll
      for (int c = 0; c < NCLS; ++c)
        cw[c] += (float)__popcll(__ballot(t == c)) * ((lane == 0) ? 1.f : 0.f);
    }
#pragma unroll
    for (int off = 32; off > 0; off >>= 1) ce += __shfl_down(ce, off);
    if (lane == 0) {
      ce_w[wid] = ce;
#pragma unroll
      for (int c = 0; c < NCLS; ++c) cw_w[wid][c] = cw[c];
    }
  }
  __syncthreads();

  if (tid == 0) {
    float ceb = 0.f, cb[NCLS];
#pragma unroll
    for (int c = 0; c < NCLS; ++c) cb[c] = 0.f;
#pragma unroll
    for (int w = 0; w < NACT; ++w) {
      ceb += ce_w[w];
#pragma unroll
      for (int c = 0; c < NCLS; ++c) cb[c] += cw_w[w][c];
    }
    float* sp = part + (size_t)bid * SLICEP + SLICE;
    sp[0] = s2[0] + s2[1];   // sumsq
    sp[1] = s3[0] + s3[1];   // l1
    sp[2] = ceb;             // ce
#pragma unroll
    for (int c = 0; c < NCLS; ++c) sp[3 + c] = cb[c];
  }
}

// Fold nblk private slices for one (class, 32-col group) -> qpart[block].
// Last block to finish also finalizes. Completion test is wrap-safe modulo
// (any 112 consecutive counter values hit residue NRED-1 exactly once), so
// `done` never needs zeroing and each launch advances it by exactly NRED.
__global__ __launch_bounds__(256) void k_reduce_fin(const float* __restrict__ part,
                                                    double* __restrict__ qpart,
                                                    unsigned* __restrict__ done,
                                                    float* __restrict__ out,
                                                    int nblk) {
  const int c  = blockIdx.x >> 4;
  const int cg = blockIdx.x & 15;
  const int t  = threadIdx.x;
  const int col = cg * 32 + (t & 31);
  const int sl0 = t >> 5;   // 0..7

  float s = 0.f;
#pragma unroll 4
  for (int sl = sl0; sl < nblk; sl += 8)
    s += part[(size_t)sl * SLICEP + c * DDIM + col];

  __shared__ float red[8][33];
  red[sl0][t & 31] = s;
  __syncthreads();

  if (t < 32) {
    float S = 0.f;
#pragma unroll
    for (int i = 0; i < 8; ++i) S += red[i][t];
    float q = S * S;
#pragma unroll
    for (int off = 16; off > 0; off >>= 1) q += __shfl_down(q, off);
    if (t == 0) qpart[blockIdx.x] = (double)q;
  }

  // Completion protocol: release own qpart, count; last block finalizes.
  __shared__ bool amlast;
  __syncthreads();
  if (t == 0) {
    __threadfence();
    amlast = ((atomicAdd(done, 1u) + 1u) % (unsigned)NRED == 0u);
  }
  __syncthreads();
  if (!amlast) return;
  __threadfence();   // acquire: all qpart now visible

  // ---- finalize with this block's 256 threads ----
  const int lane = t & 63, wid = t >> 6;
  double ss = 0.0, l1 = 0.0, ce = 0.0;
  float cnt[NCLS];
#pragma unroll
  for (int k = 0; k < NCLS; ++k) cnt[k] = 0.f;
  for (int sl = t; sl < nblk; sl += 256) {
    const float* sp = part + (size_t)sl * SLICEP + SLICE;
    ss += (double)sp[0];
    l1 += (double)sp[1];
    ce += (double)sp[2];
#pragma unroll
    for (int k = 0; k < NCLS; ++k) cnt[k] += sp[3 + k];
  }
#pragma unroll
  for (int off = 32; off > 0; off >>= 1) {
    ss += __shfl_down(ss, off);
    l1 += __shfl_down(l1, off);
    ce += __shfl_down(ce, off);
#pragma unroll
    for (int k = 0; k < NCLS; ++k) cnt[k] += __shfl_down(cnt[k], off);
  }
  __shared__ double lss[4], ll1[4], lce[4];
  __shared__ float lcnt[4][8];
  if (lane == 0) {
    lss[wid] = ss; ll1[wid] = l1; lce[wid] = ce;
#pragma unroll
    for (int k = 0; k < NCLS; ++k) lcnt[wid][k] = cnt[k];
  }
  __syncthreads();

  __shared__ float counts_sh[NCLS];
  __shared__ double tot[3];
  if (t == 0) {
    double a = 0, b = 0, d = 0;
    float cc[NCLS];
#pragma unroll
    for (int k = 0; k < NCLS; ++k) cc[k] = 0.f;
#pragma unroll
    for (int w = 0; w < 4; ++w) {
      a += lss[w]; b += ll1[w]; d += lce[w];
#pragma unroll
      for (int k = 0; k < NCLS; ++k) cc[k] += lcnt[w][k];
    }
    tot[0] = a; tot[1] = b; tot[2] = d;
#pragma unroll
    for (int k = 0; k < NCLS; ++k) counts_sh[k] = cc[k];
  }
  __syncthreads();

  // WCSS subtrahend: threads 0..111 each own one (class, col-group) partial.
  double myq = 0.0;
  if (t < NRED) {
    const float cn = counts_sh[t >> 4];
    myq = (cn > 0.f) ? qpart[t] / (double)cn : 0.0;
  }
#pragma unroll
  for (int off = 32; off > 0; off >>= 1) myq += __shfl_down(myq, off);
  __shared__ double qs[2];
  if (lane == 0 && wid < 2) qs[wid] = myq;
  __syncthreads();

  if (t == 0) {
    const double wcss = qs[0] + qs[1];
    const double center = (tot[0] - wcss) / (double)BATCH;
    const double cem = tot[2] / (double)BATCH;
    const double l1m = tot[1] / ((double)BATCH * (double)DDIM);
    out[0] = (float)(cem + 0.1 * center + 0.01 * l1m);
    out[1] = (float)cem;
    out[2] = (float)center;
    out[3] = (float)l1m;
  }
}

extern "C" void kernel_launch(void* const* d_in, const int* in_sizes, int n_in,
                              void* d_out, int out_size, void* d_ws, size_t ws_size,
                              hipStream_t stream) {
  const float*  outputs  = (const float*)d_in[0];
  const float4* features = (const float4*)d_in[1];
  const int*    targets  = (const int*)d_in[2];
  const float4* aw       = (const float4*)d_in[3];
  float* out = (float*)d_out;
  float* part = (float*)d_ws;

  // Largest block count whose slices + q-partials + counter fit the workspace.
  auto need = [](int nblk) { return (size_t)nblk * SLICEP * 4 + NRED * 8 + 4; };
  int nblk = 128;
  if (ws_size >= need(512)) nblk = 512;
  else if (ws_size >= need(256)) nblk = 256;
  double* qpart = (double*)((char*)d_ws + (size_t)nblk * SLICEP * 4);
  unsigned* done = (unsigned*)((char*)qpart + NRED * 8);

  switch (nblk) {
    case 512: k_main<128><<<512, 512, 0, stream>>>(features, aw, targets, outputs, part); break;
    case 256: k_main<256><<<256, 512, 0, stream>>>(features, aw, targets, outputs, part); break;
    default:  k_main<512><<<128, 512, 0, stream>>>(features, aw, targets, outputs, part); break;
  }
  k_reduce_fin<<<NRED, 256, 0, stream>>>(part, qpart, done, out, nblk);
}

// Round 11
// 59.325 us; speedup vs baseline: 1.0573x; 1.0573x over previous
//
#include <hip/hip_runtime.h>

static constexpr int BATCH  = 65536;
static constexpr int DDIM   = 512;
static constexpr int NCLS   = 7;
static constexpr int SLICE  = NCLS * DDIM;      // 3584 class-sum floats
static constexpr int SLICEP = SLICE + 16;       // + 16-float scalar chunk
// scalar chunk layout: [0]=sumsq [1]=l1 [2]=ce [3..9]=counts[0..6]
static constexpr int NRED   = NCLS * 16;        // 112 reduce blocks

typedef float f32x4 __attribute__((ext_vector_type(4)));

// Non-temporal float4 load (nt flag): no L3 allocation. Applied ONLY to the
// attention stream so features (130 MB) becomes fully L3-resident; the L3
// miss/allocate/evict path then only services the A stream. R8 profiled this
// at 78.9 us vs ~101 us (same FETCH) but bundled it with a memset dispatch;
// this round isolates it on the R9 structure.
__device__ __forceinline__ float4 ntload4(const float4* p) {
  f32x4 v = __builtin_nontemporal_load(reinterpret_cast<const f32x4*>(p));
  return make_float4(v.x, v.y, v.z, v.w);
}

// Fused main pass, 512 threads = 4 row-phases x 128 float4-columns.
// R7/R9-proven hot loop: predicated class accumulate (no branches -> no
// spill), float4 loads, unroll 2, bounds(512,6). All block results leave as
// plain coalesced stores into a private workspace slice; no hot-path atomics.
template <int RPB>
__global__ __launch_bounds__(512, 6) void k_main(const float4* __restrict__ F,
                                                 const float4* __restrict__ A,
                                                 const int* __restrict__ tg,
                                                 const float* __restrict__ outputs,
                                                 float* __restrict__ part) {
  const int tid  = threadIdx.x;
  const int bid  = blockIdx.x;
  const int c4   = tid & 127;   // float4 column (0..127)
  const int ph   = tid >> 7;    // row phase 0..3 (wave-uniform)
  const int base = bid * RPB;

  float4 acc[NCLS];
#pragma unroll
  for (int c = 0; c < NCLS; ++c) acc[c] = make_float4(0.f, 0.f, 0.f, 0.f);
  float sumsq = 0.f, l1 = 0.f;

#pragma unroll 2
  for (int r = base; r < base + RPB; r += 8) {
    const int4 ta = *reinterpret_cast<const int4*>(tg + r);      // rows r..r+3
    const int4 tb = *reinterpret_cast<const int4*>(tg + r + 4);  // rows r+4..r+7
    const size_t i0 = (size_t)(r + ph) * 128 + c4;
    const float4 f0 = F[i0];
    const float4 f1 = F[i0 + 512];        // row + 4
    const float4 w0 = ntload4(A + i0);    // nt: keep A out of L3
    const float4 w1 = ntload4(A + i0 + 512);
    const int t0 = (ph == 0) ? ta.x : (ph == 1) ? ta.y : (ph == 2) ? ta.z : ta.w;
    const int t1 = (ph == 0) ? tb.x : (ph == 1) ? tb.y : (ph == 2) ? tb.z : tb.w;

    sumsq = fmaf(f0.x, f0.x, sumsq); sumsq = fmaf(f0.y, f0.y, sumsq);
    sumsq = fmaf(f0.z, f0.z, sumsq); sumsq = fmaf(f0.w, f0.w, sumsq);
    sumsq = fmaf(f1.x, f1.x, sumsq); sumsq = fmaf(f1.y, f1.y, sumsq);
    sumsq = fmaf(f1.z, f1.z, sumsq); sumsq = fmaf(f1.w, f1.w, sumsq);
    l1 += fabsf(w0.x) + fabsf(w0.y) + fabsf(w0.z) + fabsf(w0.w) +
          fabsf(w1.x) + fabsf(w1.y) + fabsf(w1.z) + fabsf(w1.w);

#pragma unroll
    for (int c = 0; c < NCLS; ++c) {
      acc[c].x += (t0 == c) ? f0.x : 0.f;
      acc[c].y += (t0 == c) ? f0.y : 0.f;
      acc[c].z += (t0 == c) ? f0.z : 0.f;
      acc[c].w += (t0 == c) ? f0.w : 0.f;
      acc[c].x += (t1 == c) ? f1.x : 0.f;
      acc[c].y += (t1 == c) ? f1.y : 0.f;
      acc[c].z += (t1 == c) ? f1.z : 0.f;
      acc[c].w += (t1 == c) ? f1.w : 0.f;
    }
  }

  // Fold phases 1..3 onto phase 0 via LDS (2 rounds). [..][33] = conflict-free.
  __shared__ float red[256][33];
  if (ph >= 2) {
    float* row = red[(ph - 2) * 128 + c4];
#pragma unroll
    for (int c = 0; c < NCLS; ++c) {
      row[c * 4 + 0] = acc[c].x; row[c * 4 + 1] = acc[c].y;
      row[c * 4 + 2] = acc[c].z; row[c * 4 + 3] = acc[c].w;
    }
    row[28] = sumsq; row[29] = l1;
  }
  __syncthreads();
  if (ph < 2) {
    const float* row = red[ph * 128 + c4];
#pragma unroll
    for (int c = 0; c < NCLS; ++c) {
      acc[c].x += row[c * 4 + 0]; acc[c].y += row[c * 4 + 1];
      acc[c].z += row[c * 4 + 2]; acc[c].w += row[c * 4 + 3];
    }
    sumsq += row[28]; l1 += row[29];
  }
  __syncthreads();
  if (ph == 1) {
    float* row = red[c4];
#pragma unroll
    for (int c = 0; c < NCLS; ++c) {
      row[c * 4 + 0] = acc[c].x; row[c * 4 + 1] = acc[c].y;
      row[c * 4 + 2] = acc[c].z; row[c * 4 + 3] = acc[c].w;
    }
    row[28] = sumsq; row[29] = l1;
  }
  __syncthreads();

  __shared__ float s2[2], s3[2];
  if (ph == 0) {
    const float* row = red[c4];
#pragma unroll
    for (int c = 0; c < NCLS; ++c) {
      acc[c].x += row[c * 4 + 0]; acc[c].y += row[c * 4 + 1];
      acc[c].z += row[c * 4 + 2]; acc[c].w += row[c * 4 + 3];
    }
    sumsq += row[28]; l1 += row[29];

    // Plain coalesced stores into this block's private slice. No RMW.
    float4* __restrict__ myp = reinterpret_cast<float4*>(part + (size_t)bid * SLICEP);
#pragma unroll
    for (int c = 0; c < NCLS; ++c) myp[c * 128 + c4] = acc[c];

    float bs = sumsq, bl = l1;
#pragma unroll
    for (int off = 32; off > 0; off >>= 1) {
      bs += __shfl_down(bs, off);
      bl += __shfl_down(bl, off);
    }
    if ((tid & 63) == 0) { s2[tid >> 6] = bs; s3[tid >> 6] = bl; }
  }

  // CE + per-class counts over this block's rows, wave-parallel.
  constexpr int NACT = (RPB / 64 < 8) ? RPB / 64 : 8;   // active waves
  __shared__ float ce_w[8];
  __shared__ float cw_w[8][8];
  const int lane = tid & 63, wid = tid >> 6;
  if (wid < NACT) {
    float ce = 0.f;
    float cw[NCLS];
#pragma unroll
    for (int c = 0; c < NCLS; ++c) cw[c] = 0.f;
    for (int r0 = wid * 64; r0 < RPB; r0 += NACT * 64) {
      const int row = base + r0 + lane;
      const float* o = outputs + (size_t)row * NCLS;
      const float x0 = o[0], x1 = o[1], x2 = o[2], x3 = o[3],
                  x4 = o[4], x5 = o[5], x6 = o[6];
      const float m = fmaxf(fmaxf(fmaxf(x0, x1), fmaxf(x2, x3)),
                            fmaxf(fmaxf(x4, x5), x6));
      const float s = expf(x0 - m) + expf(x1 - m) + expf(x2 - m) + expf(x3 - m) +
                      expf(x4 - m) + expf(x5 - m) + expf(x6 - m);
      const int t = tg[row];
      const float xt = (t == 0) ? x0 : (t == 1) ? x1 : (t == 2) ? x2 :
                       (t == 3) ? x3 : (t == 4) ? x4 : (t == 5) ? x5 : x6;
      ce += (m - xt) + logf(s);
#pragma unroll
      for (int c = 0; c < NCLS; ++c)
        cw[c] += (float)__popcll(__ballot(t == c)) * ((lane == 0) ? 1.f : 0.f);
    }
#pragma unroll
    for (int off = 32; off > 0; off >>= 1) ce += __shfl_down(ce, off);
    if (lane == 0) {
      ce_w[wid] = ce;
#pragma unroll
      for (int c = 0; c < NCLS; ++c) cw_w[wid][c] = cw[c];
    }
  }
  __syncthreads();

  if (tid == 0) {
    float ceb = 0.f, cb[NCLS];
#pragma unroll
    for (int c = 0; c < NCLS; ++c) cb[c] = 0.f;
#pragma unroll
    for (int w = 0; w < NACT; ++w) {
      ceb += ce_w[w];
#pragma unroll
      for (int c = 0; c < NCLS; ++c) cb[c] += cw_w[w][c];
    }
    float* sp = part + (size_t)bid * SLICEP + SLICE;
    sp[0] = s2[0] + s2[1];   // sumsq
    sp[1] = s3[0] + s3[1];   // l1
    sp[2] = ceb;             // ce
#pragma unroll
    for (int c = 0; c < NCLS; ++c) sp[3 + c] = cb[c];
  }
}

// Fold nblk private slices for one (class, 32-col group) -> qpart[block].
// Last block to finish also finalizes. Completion test is wrap-safe modulo
// (any 112 consecutive counter values hit residue NRED-1 exactly once), so
// `done` never needs zeroing and each launch advances it by exactly NRED.
__global__ __launch_bounds__(256) void k_reduce_fin(const float* __restrict__ part,
                                                    double* __restrict__ qpart,
                                                    unsigned* __restrict__ done,
                                                    float* __restrict__ out,
                                                    int nblk) {
  const int c  = blockIdx.x >> 4;
  const int cg = blockIdx.x & 15;
  const int t  = threadIdx.x;
  const int col = cg * 32 + (t & 31);
  const int sl0 = t >> 5;   // 0..7

  float s = 0.f;
#pragma unroll 4
  for (int sl = sl0; sl < nblk; sl += 8)
    s += part[(size_t)sl * SLICEP + c * DDIM + col];

  __shared__ float red[8][33];
  red[sl0][t & 31] = s;
  __syncthreads();

  if (t < 32) {
    float S = 0.f;
#pragma unroll
    for (int i = 0; i < 8; ++i) S += red[i][t];
    float q = S * S;
#pragma unroll
    for (int off = 16; off > 0; off >>= 1) q += __shfl_down(q, off);
    if (t == 0) qpart[blockIdx.x] = (double)q;
  }

  // Completion protocol: release own qpart, count; last block finalizes.
  __shared__ bool amlast;
  __syncthreads();
  if (t == 0) {
    __threadfence();
    amlast = ((atomicAdd(done, 1u) + 1u) % (unsigned)NRED == 0u);
  }
  __syncthreads();
  if (!amlast) return;
  __threadfence();   // acquire: all qpart now visible

  // ---- finalize with this block's 256 threads ----
  const int lane = t & 63, wid = t >> 6;
  double ss = 0.0, l1 = 0.0, ce = 0.0;
  float cnt[NCLS];
#pragma unroll
  for (int k = 0; k < NCLS; ++k) cnt[k] = 0.f;
  for (int sl = t; sl < nblk; sl += 256) {
    const float* sp = part + (size_t)sl * SLICEP + SLICE;
    ss += (double)sp[0];
    l1 += (double)sp[1];
    ce += (double)sp[2];
#pragma unroll
    for (int k = 0; k < NCLS; ++k) cnt[k] += sp[3 + k];
  }
#pragma unroll
  for (int off = 32; off > 0; off >>= 1) {
    ss += __shfl_down(ss, off);
    l1 += __shfl_down(l1, off);
    ce += __shfl_down(ce, off);
#pragma unroll
    for (int k = 0; k < NCLS; ++k) cnt[k] += __shfl_down(cnt[k], off);
  }
  __shared__ double lss[4], ll1[4], lce[4];
  __shared__ float lcnt[4][8];
  if (lane == 0) {
    lss[wid] = ss; ll1[wid] = l1; lce[wid] = ce;
#pragma unroll
    for (int k = 0; k < NCLS; ++k) lcnt[wid][k] = cnt[k];
  }
  __syncthreads();

  __shared__ float counts_sh[NCLS];
  __shared__ double tot[3];
  if (t == 0) {
    double a = 0, b = 0, d = 0;
    float cc[NCLS];
#pragma unroll
    for (int k = 0; k < NCLS; ++k) cc[k] = 0.f;
#pragma unroll
    for (int w = 0; w < 4; ++w) {
      a += lss[w]; b += ll1[w]; d += lce[w];
#pragma unroll
      for (int k = 0; k < NCLS; ++k) cc[k] += lcnt[w][k];
    }
    tot[0] = a; tot[1] = b; tot[2] = d;
#pragma unroll
    for (int k = 0; k < NCLS; ++k) counts_sh[k] = cc[k];
  }
  __syncthreads();

  // WCSS subtrahend: threads 0..111 each own one (class, col-group) partial.
  double myq = 0.0;
  if (t < NRED) {
    const float cn = counts_sh[t >> 4];
    myq = (cn > 0.f) ? qpart[t] / (double)cn : 0.0;
  }
#pragma unroll
  for (int off = 32; off > 0; off >>= 1) myq += __shfl_down(myq, off);
  __shared__ double qs[2];
  if (lane == 0 && wid < 2) qs[wid] = myq;
  __syncthreads();

  if (t == 0) {
    const double wcss = qs[0] + qs[1];
    const double center = (tot[0] - wcss) / (double)BATCH;
    const double cem = tot[2] / (double)BATCH;
    const double l1m = tot[1] / ((double)BATCH * (double)DDIM);
    out[0] = (float)(cem + 0.1 * center + 0.01 * l1m);
    out[1] = (float)cem;
    out[2] = (float)center;
    out[3] = (float)l1m;
  }
}

extern "C" void kernel_launch(void* const* d_in, const int* in_sizes, int n_in,
                              void* d_out, int out_size, void* d_ws, size_t ws_size,
                              hipStream_t stream) {
  const float*  outputs  = (const float*)d_in[0];
  const float4* features = (const float4*)d_in[1];
  const int*    targets  = (const int*)d_in[2];
  const float4* aw       = (const float4*)d_in[3];
  float* out = (float*)d_out;
  float* part = (float*)d_ws;

  // Largest block count whose slices + q-partials + counter fit the workspace.
  auto need = [](int nblk) { return (size_t)nblk * SLICEP * 4 + NRED * 8 + 4; };
  int nblk = 128;
  if (ws_size >= need(512)) nblk = 512;
  else if (ws_size >= need(256)) nblk = 256;
  double* qpart = (double*)((char*)d_ws + (size_t)nblk * SLICEP * 4);
  unsigned* done = (unsigned*)((char*)qpart + NRED * 8);

  switch (nblk) {
    case 512: k_main<128><<<512, 512, 0, stream>>>(features, aw, targets, outputs, part); break;
    case 256: k_main<256><<<256, 512, 0, stream>>>(features, aw, targets, outputs, part); break;
    default:  k_main<512><<<128, 512, 0, stream>>>(features, aw, targets, outputs, part); break;
  }
  k_reduce_fin<<<NRED, 256, 0, stream>>>(part, qpart, done, out, nblk);
}